// Round 17
// baseline (372.116 us; speedup 1.0000x reference)
//
#include <hip/hip_runtime.h>

// out[b,i,j,d] = sum_{k<c} A[b,i,k,d] * B[b,k,j,d]   for i,j < c, else 0
// A: (256,64,64,32) f32, strides: b:131072, i:2048, k:32, d:1
// B: (256,64,64,32) f32, strides: b:131072, k:2048, j:32, d:1
//
// v17: restructured decomposition. Block = (batch, 16-row i-quarter),
// 512 thr, thread = (d-pair, j-pair), acc 16i*2j*2d = 64 VGPR.
// Per K-tile (KT=4): stage B 32KB + A 8KB via global_load_lds (DMA gives the
// loads-in-flight the compiler refuses in registers: v9-v15), compute from
// LDS (A broadcast, B 4-way minor). Each staged B byte read 16x (i-rows);
// per-CU working set = ONE batch tile -> no v16 L2 thrash (FETCH 178MB).
// Grid 1024: w = (b&7) + 8*(q + 4*(b>>3)): batch's quarters on same XCD
// (B L2-shared), adjacent CUs; 4 different-c batches per CU (balance).
// No sort, no workspace. Whale floor ~27us FMA + ~25us memory.

#define BATCH 256
#define NN 64
#define ND 32
#define BSTRIDE (NN * NN * ND)    // 131072
#define RSTRIDE (NN * ND)         // 2048
#define QROWS 16                  // i-rows per block
#define KT 4
#define BT_F (KT * NN * ND)       // 8192 floats = 32 KB
#define AT_F (QROWS * KT * ND)    // 2048 floats = 8 KB

#define GLOAD_LDS16(GP, LP)                                                    \
    __builtin_amdgcn_global_load_lds(                                          \
        (const __attribute__((address_space(1))) float*)(GP),                  \
        (__attribute__((address_space(3))) float*)(LP), 16, 0, 0)

#define COMPUTE_KK(kk)                                                         \
    {                                                                          \
        const float2 bv0 = *reinterpret_cast<const float2*>(                   \
            &Bt[(kk) * (NN * ND) + j0 * ND + d0]);                             \
        const float2 bv1 = *reinterpret_cast<const float2*>(                   \
            &Bt[(kk) * (NN * ND) + (j0 + 1) * ND + d0]);                       \
        _Pragma("unroll")                                                      \
        for (int u = 0; u < QROWS; ++u) {                                      \
            const float2 a = *reinterpret_cast<const float2*>(                 \
                &At[u * (KT * ND) + (kk) * ND + d0]);                          \
            acc[u][0][0] = fmaf(a.x, bv0.x, acc[u][0][0]);                     \
            acc[u][0][1] = fmaf(a.y, bv0.y, acc[u][0][1]);                     \
            acc[u][1][0] = fmaf(a.x, bv1.x, acc[u][1][0]);                     \
            acc[u][1][1] = fmaf(a.y, bv1.y, acc[u][1][1]);                     \
        }                                                                      \
    }

__global__ __launch_bounds__(512, 4) void mp_kernel(
    const float* __restrict__ A, const float* __restrict__ B,
    const int* __restrict__ counts, float* __restrict__ out)
{
    __shared__ float Bt[BT_F];
    __shared__ float At[AT_F];

    // w = (b&7) + 8*(q + 4*(b>>3)) ; decode:
    const int w  = (int)blockIdx.x;
    const int x  = w & 7;
    const int s  = w >> 3;
    const int q  = s & 3;
    const int b  = x + ((s >> 2) << 3);
    const int i0 = q * QROWS;

    const int c   = counts[b];
    const int tid = (int)threadIdx.x;
    const int d2  = tid & 15;            // d-pair: d0 = 2*d2
    const int j2  = tid >> 4;            // 0..31: j0 = 2*j2
    const int d0  = d2 << 1;
    const int j0  = j2 << 1;

    const size_t base = (size_t)b * BSTRIDE;
    float* __restrict__ Ob = out + base + (size_t)i0 * RSTRIDE + (size_t)j0 * ND + d0;

    // fast path: whole i-quarter invalid -> zero-fill and retire
    if (i0 >= c) {
        const float2 z = make_float2(0.f, 0.f);
        #pragma unroll
        for (int u = 0; u < QROWS; ++u) {
            *reinterpret_cast<float2*>(Ob + (size_t)u * RSTRIDE)      = z;
            *reinterpret_cast<float2*>(Ob + (size_t)u * RSTRIDE + ND) = z;
        }
        return;
    }

    const float4* Bg4 = reinterpret_cast<const float4*>(B + base);  // + t*2048 + g4
    const float*  Ag  = A + base;

    float acc[QROWS][2][2];
    #pragma unroll
    for (int u = 0; u < QROWS; ++u) {
        acc[u][0][0] = 0.f; acc[u][0][1] = 0.f;
        acc[u][1][0] = 0.f; acc[u][1][1] = 0.f;
    }

    const int nt = (c + KT - 1) / KT;
    // A-staging source for this thread: row = i0 + (tid>>5), 16B seg = tid&31
    const float* Asrc_row = Ag + (size_t)(i0 + (tid >> 5)) * RSTRIDE;
    const int    Aseg     = (tid & 31) * 4;   // float offset of 16B segment

    for (int t = 0; t < nt; ++t) {
        // ---- stage B-tile (32KB contiguous: 4 k-rows) : 4 instr/thread
        #pragma unroll
        for (int s4 = 0; s4 < 4; ++s4)
            GLOAD_LDS16(Bg4 + (size_t)t * 2048 + s4 * 512 + tid,
                        reinterpret_cast<float4*>(Bt) + s4 * 512 + tid);
        // ---- stage A-tile (16 rows x 512B, row-contig source) : 1 instr
        GLOAD_LDS16(Asrc_row + t * (KT * ND) + Aseg,
                    reinterpret_cast<float4*>(At) + tid);

        asm volatile("s_waitcnt vmcnt(0)" ::: "memory");
        __syncthreads();                 // tile landed

        const int rem  = c - t * KT;
        const int kmax = (rem >= KT) ? KT : rem;
        if (kmax == KT) {
            COMPUTE_KK(0); COMPUTE_KK(1); COMPUTE_KK(2); COMPUTE_KK(3);
        } else {
            for (int kk = 0; kk < kmax; ++kk) COMPUTE_KK(kk);
        }
        __syncthreads();                 // reads done before next overwrite
    }

    // masked store (output poisoned before timing -> write everything)
    const bool jv0 = (j0 < c);
    const bool jv1 = (j0 + 1 < c);
    #pragma unroll
    for (int u = 0; u < QROWS; ++u) {
        const bool iv = (i0 + u) < c;
        const float2 o0 = (iv && jv0) ? make_float2(acc[u][0][0], acc[u][0][1])
                                      : make_float2(0.f, 0.f);
        const float2 o1 = (iv && jv1) ? make_float2(acc[u][1][0], acc[u][1][1])
                                      : make_float2(0.f, 0.f);
        *reinterpret_cast<float2*>(Ob + (size_t)u * RSTRIDE)      = o0;
        *reinterpret_cast<float2*>(Ob + (size_t)u * RSTRIDE + ND) = o1;
    }
}

extern "C" void kernel_launch(void* const* d_in, const int* in_sizes, int n_in,
                              void* d_out, int out_size, void* d_ws, size_t ws_size,
                              hipStream_t stream)
{
    const float* A      = (const float*)d_in[0];
    const float* B      = (const float*)d_in[1];
    const int*   counts = (const int*)d_in[2];
    float* out = (float*)d_out;

    mp_kernel<<<dim3(BATCH * 4), dim3(512), 0, stream>>>(A, B, counts, out);
}

// Round 18
// 81.417 us; speedup vs baseline: 4.5705x; 4.5705x over previous
//
#include <hip/hip_runtime.h>

// out[b,i,j,d] = sum_{k<c} A[b,i,k,d] * B[b,k,j,d]   for i,j < c, else 0
// A: (256,64,64,32) f32, strides: b:131072, i:2048, k:32, d:1
// B: (256,64,64,32) f32, strides: b:131072, k:2048, j:32, d:1
//
// v18: v10's structure (direct loads + XCD-bucketed longest-first sort +
// T19 clustering) re-budgeted to fit FULL K4 clustering in the 64-VGPR tier
// the compiler insists on (v9-v15 post-mortems):
//   ICHUNK 8->4 (acc 32->16 regs), K4 cluster = 32 loads in flight
//   demand ~= 32 + 16 + 10 addr < 64  -> RA cannot veto, SGB pins the order.
// One exposed L2 latency per 4 k-iters (v10: per 2) at same FMA duty.
// 4096 finer items smooth the whale tail. LDS staging is dead (v7/v16/v17:
// FETCH 178-237MB L2 thrash, stage-drain serialization at 3.6 FLOP/byte).

#define BATCH 256
#define NN 64
#define ND 32
#define BSTRIDE (NN * NN * ND)   // 131072
#define RSTRIDE (NN * ND)        // 2048
#define ICHUNK 4
#define NITEMS (BATCH * 16)      // 4096, item w = b*16 + q

// ---------------- prologue: per-XCD-bucket counting sort --------------------
__global__ __launch_bounds__(512) void mp_prologue(
    const int* __restrict__ counts, int* __restrict__ items)
{
    __shared__ int cLds[BATCH];
    __shared__ int hist[8][NN + 1];  // key 0..63 = valid (64-c): whales first; 64 = zero-fill
    __shared__ int offs[8][NN + 1];
    const int tid = (int)threadIdx.x;

    for (int x = tid; x < 8 * (NN + 1); x += 512)
        (&hist[0][0])[x] = 0;
    for (int b = tid; b < BATCH; b += 512) cLds[b] = counts[b];
    __syncthreads();

    for (int w = tid; w < NITEMS; w += 512) {
        const int b = w >> 4, q = w & 15;
        const int c = cLds[b];
        const int key = (q * ICHUNK < c) ? (NN - c) : NN;
        atomicAdd(&hist[b & 7][key], 1);
    }
    __syncthreads();

    if (tid < 8) {  // serial 65-entry exclusive scan per bucket
        int acc = 0;
        for (int k = 0; k <= NN; ++k) { offs[tid][k] = acc; acc += hist[tid][k]; }
    }
    __syncthreads();

    for (int w = tid; w < NITEMS; w += 512) {
        const int b = w >> 4, q = w & 15;
        const int c = cLds[b];
        const int key = (q * ICHUNK < c) ? (NN - c) : NN;
        const int pos = atomicAdd(&offs[b & 7][key], 1);  // rank within bucket
        items[pos * 8 + (b & 7)] = w;                     // slot%8 == b%8
    }
}

// ---------------- main body: K4 full cluster in the 64-VGPR tier ------------
__device__ __forceinline__ void mp_body(
    int b, int q,
    const float* __restrict__ A, const float* __restrict__ B,
    const int* __restrict__ counts, float* __restrict__ out)
{
    const int i0 = q << 2;
    const int c  = counts[b];
    const int tid = (int)threadIdx.x;
    const int d  = tid & 31;             // channel
    const int jg = tid >> 5;             // 0..15, group of 4 j's
    const int jb = jg << 2;              // j base

    const size_t base = (size_t)b * BSTRIDE;
    float* __restrict__ Ob = out + base + (size_t)i0 * RSTRIDE + (size_t)jb * ND + d;

    if (i0 >= c) {
        #pragma unroll
        for (int ii = 0; ii < ICHUNK; ++ii)
            #pragma unroll
            for (int jj = 0; jj < 4; ++jj)
                Ob[(size_t)ii * RSTRIDE + jj * ND] = 0.0f;
        return;
    }

    const float* __restrict__ Ai = A + base + (size_t)i0 * RSTRIDE + d;
    const float* __restrict__ Bb = B + base + (size_t)jb * ND + d;

    float acc[ICHUNK][4];
    #pragma unroll
    for (int ii = 0; ii < ICHUNK; ++ii)
        #pragma unroll
        for (int jj = 0; jj < 4; ++jj)
            acc[ii][jj] = 0.0f;

    const bool waveActive = (((tid >> 6) << 3) < c);

    if (waveActive) {
        const int c4 = c & ~3;
        int k = 0;
        #pragma unroll 1
        for (; k < c4; k += 4) {
            // ---- phase 1: issue ALL 32 loads (4 k-steps), 32+16 regs < 64 tier
            float av[4][ICHUNK];
            float bv[4][4];
            #pragma unroll
            for (int kk = 0; kk < 4; ++kk) {
                #pragma unroll
                for (int ii = 0; ii < ICHUNK; ++ii)
                    av[kk][ii] = Ai[(size_t)ii * RSTRIDE + (size_t)(k + kk) * ND];
                #pragma unroll
                for (int jj = 0; jj < 4; ++jj)
                    bv[kk][jj] = Bb[(size_t)(k + kk) * RSTRIDE + jj * ND];
            }
            // ---- phase 2: 64 FMAs
            #pragma unroll
            for (int kk = 0; kk < 4; ++kk)
                #pragma unroll
                for (int ii = 0; ii < ICHUNK; ++ii)
                    #pragma unroll
                    for (int jj = 0; jj < 4; ++jj)
                        acc[ii][jj] = fmaf(av[kk][ii], bv[kk][jj], acc[ii][jj]);

            // ---- T19 pins: [addr VALU][32 VMEM_READ][64 VALU]
            __builtin_amdgcn_sched_group_barrier(0x002, 16, 0);
            __builtin_amdgcn_sched_group_barrier(0x020, 32, 0);
            __builtin_amdgcn_sched_group_barrier(0x002, 64, 0);
        }
        // tail (<=3 iterations)
        #pragma unroll 1
        for (; k < c; ++k) {
            float av[ICHUNK];
            #pragma unroll
            for (int ii = 0; ii < ICHUNK; ++ii)
                av[ii] = Ai[(size_t)ii * RSTRIDE + (size_t)k * ND];
            float bv[4];
            #pragma unroll
            for (int jj = 0; jj < 4; ++jj)
                bv[jj] = Bb[(size_t)k * RSTRIDE + jj * ND];
            #pragma unroll
            for (int ii = 0; ii < ICHUNK; ++ii)
                #pragma unroll
                for (int jj = 0; jj < 4; ++jj)
                    acc[ii][jj] = fmaf(av[ii], bv[jj], acc[ii][jj]);
        }
    }

    #pragma unroll
    for (int ii = 0; ii < ICHUNK; ++ii) {
        const bool iv = (i0 + ii) < c;
        #pragma unroll
        for (int jj = 0; jj < 4; ++jj) {
            const bool v = iv && ((jb + jj) < c);
            Ob[(size_t)ii * RSTRIDE + jj * ND] = v ? acc[ii][jj] : 0.0f;
        }
    }
}

__global__ __launch_bounds__(512, 4) void mp_kernel_sorted(
    const float* __restrict__ A, const float* __restrict__ B,
    const int* __restrict__ counts, float* __restrict__ out,
    const int* __restrict__ items)
{
    const int w = items[blockIdx.x];
    mp_body(w >> 4, w & 15, A, B, counts, out);
}

__global__ __launch_bounds__(512, 4) void mp_kernel_direct(
    const float* __restrict__ A, const float* __restrict__ B,
    const int* __restrict__ counts, float* __restrict__ out)
{
    mp_body(blockIdx.x & (BATCH - 1), blockIdx.x >> 8, A, B, counts, out);
}

extern "C" void kernel_launch(void* const* d_in, const int* in_sizes, int n_in,
                              void* d_out, int out_size, void* d_ws, size_t ws_size,
                              hipStream_t stream)
{
    const float* A      = (const float*)d_in[0];
    const float* B      = (const float*)d_in[1];
    const int*   counts = (const int*)d_in[2];
    float* out = (float*)d_out;

    if (ws_size >= NITEMS * sizeof(int)) {
        int* items = (int*)d_ws;
        mp_prologue<<<dim3(1), dim3(512), 0, stream>>>(counts, items);
        mp_kernel_sorted<<<dim3(NITEMS), dim3(512), 0, stream>>>(A, B, counts, out, items);
    } else {
        mp_kernel_direct<<<dim3(NITEMS), dim3(512), 0, stream>>>(A, B, counts, out);
    }
}